// Round 1
// baseline (286.579 us; speedup 1.0000x reference)
//
#include <hip/hip_runtime.h>
#include <hip/hip_bf16.h>

#define BATCH 16
#define HH 56
#define WW 56
#define CC 384
#define HWW (HH*WW)          // 3136
#define MM (BATCH*HWW)       // 50176
#define CQ 96
#define BKK 64
#define LDSP 72              // padded LDS K stride (bf16 elems)

typedef __attribute__((ext_vector_type(8))) short bf16x8;
typedef __attribute__((ext_vector_type(4))) short bf16x4;
typedef __attribute__((ext_vector_type(4))) float f32x4;

__device__ __forceinline__ unsigned short f2bf(float f) {
    union { float f; unsigned u; } v; v.f = f;
    unsigned r = v.u + 0x7fffu + ((v.u >> 16) & 1u);
    return (unsigned short)(r >> 16);
}
__device__ __forceinline__ float bf2f(unsigned short h) {
    union { unsigned u; float f; } v; v.u = ((unsigned)h) << 16;
    return v.f;
}

// MODE 0: x_c = x @ w_c            (A = x fp32, out bf16)
// MODE 1: x_h = shift(x) @ w_h     (A = per-channel-shifted x, out bf16)
// MODE 2: out = (lam_hw*x_h + lam_c*x_c) @ w_p   (A combined bf16, out fp32)
template<int MODE>
__global__ __launch_bounds__(256)
void gemm_k(const float* __restrict__ xf,
            const unsigned short* __restrict__ xh,
            const unsigned short* __restrict__ xc,
            const float2* __restrict__ lam,
            const unsigned short* __restrict__ wT,   // bf16, wT[n*CC + k]
            const float* __restrict__ bias,
            unsigned short* __restrict__ out_bf,
            float* __restrict__ out_f)
{
    __shared__ unsigned short As[128][LDSP];
    __shared__ unsigned short Bs[128][LDSP];

    const int tid = threadIdx.x;
    const int m0 = blockIdx.x * 128;
    const int n0 = blockIdx.y * 128;

    const int lane = tid & 63;
    const int wid  = tid >> 6;
    const int l16  = lane & 15;
    const int lhi  = lane >> 4;
    const int wm = (wid >> 1) * 64;
    const int wn = (wid & 1) * 64;

    f32x4 acc[4][4];
    #pragma unroll
    for (int i = 0; i < 4; i++)
        #pragma unroll
        for (int j = 0; j < 4; j++) acc[i][j] = (f32x4)0.f;

    // per-thread A staging precompute
    const float* aptr[8];
    int ah[8];
    if (MODE <= 1) {
        int rowg = tid >> 4;
        #pragma unroll
        for (int i = 0; i < 8; i++) {
            int m = m0 + rowg + 16*i;
            int b = m / HWW;
            int rem = m - b*HWW;
            ah[i] = rem / WW;
            aptr[i] = xf + (size_t)m * CC;
        }
    }
    int btok[4];
    if (MODE == 2) {
        int rowg = tid >> 3;
        #pragma unroll
        for (int i = 0; i < 4; i++) {
            int m = m0 + rowg + 32*i;
            btok[i] = m / HWW;
        }
    }

    for (int kt = 0; kt < CC/BKK; ++kt) {
        const int kb = kt * BKK;
        // ---- stage B tile (w^T, bf16, coalesced 16B) ----
        {
            int ko = tid & 7;
            int nr = tid >> 3;
            #pragma unroll
            for (int i = 0; i < 4; i++) {
                int n = nr + 32*i;
                bf16x8 v = *(const bf16x8*)(wT + (size_t)(n0 + n)*CC + kb + ko*8);
                *(bf16x8*)&Bs[n][ko*8] = v;
            }
        }
        // ---- stage A tile ----
        if (MODE == 0) {
            int kq = tid & 15;
            int rowg = tid >> 4;
            #pragma unroll
            for (int i = 0; i < 8; i++) {
                float4 v = *(const float4*)(aptr[i] + kb + kq*4);
                bf16x4 b4;
                b4[0] = (short)f2bf(v.x); b4[1] = (short)f2bf(v.y);
                b4[2] = (short)f2bf(v.z); b4[3] = (short)f2bf(v.w);
                *(bf16x4*)&As[rowg + 16*i][kq*4] = b4;
            }
        } else if (MODE == 1) {
            int kq = tid & 15;
            int rowg = tid >> 4;
            // source row = h + d; d pattern per k%8 group:
            // k%8 in 0..3  -> d = { 2, 1, 0,-1}
            // k%8 in 4..7  -> d = {-2,-1, 0, 1}
            const int d0 = (kq & 1) ? -2 : 2;
            const int d1 = (kq & 1) ? -1 : 1;
            #pragma unroll
            for (int i = 0; i < 8; i++) {
                int h = ah[i];
                const float* p = aptr[i] + kb + kq*4;
                float v0 = ((unsigned)(h + d0) < HH) ? p[d0*WW*CC + 0] : 0.f;
                float v1 = ((unsigned)(h + d1) < HH) ? p[d1*WW*CC + 1] : 0.f;
                float v2 = p[2];
                float v3 = ((unsigned)(h - d1) < HH) ? p[-d1*WW*CC + 3] : 0.f;
                bf16x4 b4;
                b4[0] = (short)f2bf(v0); b4[1] = (short)f2bf(v1);
                b4[2] = (short)f2bf(v2); b4[3] = (short)f2bf(v3);
                *(bf16x4*)&As[rowg + 16*i][kq*4] = b4;
            }
        } else {
            int ko = tid & 7;
            int rowg = tid >> 3;
            #pragma unroll
            for (int i = 0; i < 4; i++) {
                int m = m0 + rowg + 32*i;
                size_t base = (size_t)m*CC + kb + ko*8;
                bf16x8 vh = *(const bf16x8*)(xh + base);
                bf16x8 vc = *(const bf16x8*)(xc + base);
                const float2* lp = lam + btok[i]*CC + kb + ko*8;
                bf16x8 o;
                #pragma unroll
                for (int j = 0; j < 8; j++) {
                    float2 l = lp[j];
                    float v = l.x * bf2f((unsigned short)vh[j])
                            + l.y * bf2f((unsigned short)vc[j]);
                    o[j] = (short)f2bf(v);
                }
                *(bf16x8*)&As[rowg + 32*i][ko*8] = o;
            }
        }
        __syncthreads();
        // ---- MFMA ----
        #pragma unroll
        for (int kk = 0; kk < BKK; kk += 32) {
            bf16x8 af[4], bfr[4];
            #pragma unroll
            for (int mi = 0; mi < 4; mi++)
                af[mi] = *(const bf16x8*)&As[wm + mi*16 + l16][kk + lhi*8];
            #pragma unroll
            for (int ni = 0; ni < 4; ni++)
                bfr[ni] = *(const bf16x8*)&Bs[wn + ni*16 + l16][kk + lhi*8];
            #pragma unroll
            for (int mi = 0; mi < 4; mi++)
                #pragma unroll
                for (int ni = 0; ni < 4; ni++)
                    acc[mi][ni] = __builtin_amdgcn_mfma_f32_16x16x32_bf16(
                        af[mi], bfr[ni], acc[mi][ni], 0, 0, 0);
        }
        __syncthreads();
    }

    // ---- epilogue: D row=(lane>>4)*4+j, col=lane&15 ----
    #pragma unroll
    for (int ni = 0; ni < 4; ni++) {
        int n = n0 + wn + ni*16 + l16;
        float bs = bias[n];
        #pragma unroll
        for (int mi = 0; mi < 4; mi++) {
            int r = m0 + wm + mi*16 + lhi*4;
            #pragma unroll
            for (int j = 0; j < 4; j++) {
                float v = acc[mi][ni][j] + bs;
                if (MODE == 2) out_f[(size_t)(r + j)*CC + n] = v;
                else           out_bf[(size_t)(r + j)*CC + n] = f2bf(v);
            }
        }
    }
}

// column sums of (2*x_h + x_c) per (batch, channel)
__global__ __launch_bounds__(256)
void reduce_k(const unsigned short* __restrict__ xh,
              const unsigned short* __restrict__ xc,
              float* __restrict__ a_sum)
{
    const int lane = threadIdx.x & 63;
    const int w = threadIdx.x >> 6;
    const int b = blockIdx.x;
    const int cpair = blockIdx.y * 64 + lane;   // channel pair index (0..191)
    const int z = blockIdx.z;
    const unsigned* ph = (const unsigned*)xh;
    const unsigned* pc = (const unsigned*)xc;
    int t0 = b*HWW + z*392 + w*98;
    float s0 = 0.f, s1 = 0.f;
    for (int t = 0; t < 98; ++t) {
        size_t idx = (size_t)(t0 + t) * (CC/2) + cpair;
        unsigned uh = ph[idx], uc = pc[idx];
        s0 += 2.f*bf2f((unsigned short)(uh & 0xffffu)) + bf2f((unsigned short)(uc & 0xffffu));
        s1 += 2.f*bf2f((unsigned short)(uh >> 16))     + bf2f((unsigned short)(uc >> 16));
    }
    atomicAdd(&a_sum[b*CC + 2*cpair],     s0);
    atomicAdd(&a_sum[b*CC + 2*cpair + 1], s1);
}

__global__ void r1_k(const float* __restrict__ a_sum,
                     const float* __restrict__ w_r1,
                     const float* __restrict__ b_r1,
                     float* __restrict__ r1)
{
    int b = blockIdx.x;
    int j = threadIdx.x;
    if (j >= CQ) return;
    float s = b_r1[j];
    const float inv = 1.f / (float)HWW;
    for (int c = 0; c < CC; c++)
        s += a_sum[b*CC + c] * inv * w_r1[c*CQ + j];
    float g = 0.5f * s * (1.f + erff(s * 0.70710678118654752f));   // exact gelu
    r1[b*CQ + j] = g;
}

__global__ __launch_bounds__(256)
void lam_k(const float* __restrict__ r1,
           const float* __restrict__ w_r2,
           const float* __restrict__ b_r2,
           float2* __restrict__ lam)
{
    int idx = blockIdx.x*256 + threadIdx.x;   // 0..B*CC-1
    int b = idx / CC;
    int c = idx - b*CC;
    float s0 = b_r2[3*c], s1 = b_r2[3*c+1], s2 = b_r2[3*c+2];
    for (int q = 0; q < CQ; q++) {
        float rv = r1[b*CQ + q];
        const float* wp = w_r2 + (size_t)q*(3*CC) + 3*c;
        s0 += rv*wp[0]; s1 += rv*wp[1]; s2 += rv*wp[2];
    }
    float m = fmaxf(s0, fmaxf(s1, s2));
    float e0 = expf(s0 - m), e1 = expf(s1 - m), e2 = expf(s2 - m);
    float d = e0 + e1 + e2;
    lam[idx] = make_float2((e0 + e1)/d, e2/d);
}

// weights: fp32 (k,n) row-major  ->  bf16 transposed (n,k)
__global__ void prep_k(const float* __restrict__ w_h,
                       const float* __restrict__ w_c,
                       const float* __restrict__ w_p,
                       unsigned short* __restrict__ wTh,
                       unsigned short* __restrict__ wTc,
                       unsigned short* __restrict__ wTp)
{
    int idx = blockIdx.x*256 + threadIdx.x;   // 0..CC*CC-1
    const float* src = blockIdx.y == 0 ? w_h : (blockIdx.y == 1 ? w_c : w_p);
    unsigned short* dst = blockIdx.y == 0 ? wTh : (blockIdx.y == 1 ? wTc : wTp);
    int n = idx / CC, k = idx - n*CC;
    dst[idx] = f2bf(src[k*CC + n]);
}

extern "C" void kernel_launch(void* const* d_in, const int* in_sizes, int n_in,
                              void* d_out, int out_size, void* d_ws, size_t ws_size,
                              hipStream_t stream)
{
    const float* x    = (const float*)d_in[0];
    const float* w_h  = (const float*)d_in[1];
    const float* b_h  = (const float*)d_in[2];
    const float* w_c  = (const float*)d_in[3];
    const float* b_c  = (const float*)d_in[4];
    const float* w_r1 = (const float*)d_in[5];
    const float* b_r1 = (const float*)d_in[6];
    const float* w_r2 = (const float*)d_in[7];
    const float* b_r2 = (const float*)d_in[8];
    const float* w_p  = (const float*)d_in[9];
    const float* b_p  = (const float*)d_in[10];
    float* out = (float*)d_out;

    char* ws = (char*)d_ws;
    const size_t XB = (size_t)MM * CC * 2;         // 38,535,168
    unsigned short* xh  = (unsigned short*)(ws);
    unsigned short* xc  = (unsigned short*)(ws + XB);
    unsigned short* wTh = (unsigned short*)(ws + 2*XB);
    unsigned short* wTc = (unsigned short*)(ws + 2*XB + 294912);
    unsigned short* wTp = (unsigned short*)(ws + 2*XB + 2*294912);
    float* a_sum        = (float*)(ws + 2*XB + 3*294912);
    float* r1           = (float*)(ws + 2*XB + 3*294912 + 24576);
    float2* lam         = (float2*)(ws + 2*XB + 3*294912 + 24576 + 6144);

    prep_k<<<dim3((CC*CC)/256, 3), 256, 0, stream>>>(w_h, w_c, w_p, wTh, wTc, wTp);
    hipMemsetAsync(a_sum, 0, BATCH*CC*sizeof(float), stream);

    dim3 ggrid(MM/128, CC/128);
    gemm_k<1><<<ggrid, 256, 0, stream>>>(x, nullptr, nullptr, nullptr, wTh, b_h, xh, nullptr);
    gemm_k<0><<<ggrid, 256, 0, stream>>>(x, nullptr, nullptr, nullptr, wTc, b_c, xc, nullptr);
    reduce_k<<<dim3(BATCH, 3, 8), 256, 0, stream>>>(xh, xc, a_sum);
    r1_k<<<BATCH, 128, 0, stream>>>(a_sum, w_r1, b_r1, r1);
    lam_k<<<(BATCH*CC)/256, 256, 0, stream>>>(r1, w_r2, b_r2, lam);
    gemm_k<2><<<ggrid, 256, 0, stream>>>(nullptr, xh, xc, lam, wTp, b_p, nullptr, out);
}